// Round 11
// baseline (3075.485 us; speedup 1.0000x reference)
//
#include <hip/hip_runtime.h>
#include <cstdint>
#include <cstddef>

// LSTM B=256,S=512,C=64,H=128, 2 layers, gates i,f,g,o (torch order).
// Round 14: single-launch producer/consumer overlap; intrinsic MFMA restored.
// asm-MFMA line abandoned (2 correctness failures: inline asm bypasses the
// GCNHazardRecognizer; residual init-edge hazard after exit-edge fence).
// The ~125us serial prep gap is attacked structurally: ONE launch of 2112
// blocks; blocks 0-63 = recurrence (round-8 intrinsic structure, 565us,
// passed), blocks 64-2111 = xg producer (blk=p&63, tch=p>>6). Producer:
// stores -> threadfence(all) -> syncthreads -> tid0 atomicAdd(count[tch],
// release). Consumer: acquire-spin count[c]==64 before prefetching the
// first xg slot of chunk c (uniform branch, ~1 L2 load / 16 steps). No
// deadlock under any dispatch order (producers never wait). Replay-safe:
// memsetAsync(count) at stream head; xg is input-deterministic so
// cross-replay re-reads are byte-identical. Pattern proven by the round-0
// baseline (tokened flags, agent atomics, passed).
//
// MFMA 16x16x32 bf16 frags (verified rounds 1-13):
//   A[m=lane&15][k=(lane>>4)*8+j], B == W[n=lane&15][k] 16B row chunk,
//   D[m=4*(lane>>4)+reg][n=lane&15]
// Consumer valid tile rows: m&3==0 (batch row = m>>2); A-frag reads 4-way
// same-address broadcast per r-quad.

#define S_LEN 512
#define B_SZ  256
#define C_IN  64
#define HDIM  128
#define NBLK  64                     // consumer blocks, 4 batch rows each
#define NPROD (64 * 32)              // producer blocks
#define XG_TSTRIDE (64 * 512 * 4)    // shorts per timestep slot of xg (=131072)

using short4v = __attribute__((ext_vector_type(4))) short;   // 4 bf16
using short8  = __attribute__((ext_vector_type(8))) short;   // 8 bf16
using float4v = __attribute__((ext_vector_type(4))) float;

template<bool V> struct Flag { static constexpr bool value = V; };

__device__ __forceinline__ unsigned short f2b(float f) {
    union { float f; unsigned int u; } v; v.f = f;
    unsigned int u = v.u;
    return (unsigned short)((u + 0x7FFFu + ((u >> 16) & 1u)) >> 16);
}
__device__ __forceinline__ float b2f(unsigned short s) {
    union { unsigned int u; float f; } v; v.u = ((unsigned int)s) << 16;
    return v.f;
}
// lean activations: sigma = rcp(1+exp2(-x*log2e)), tanh = 1-2*rcp(1+exp2(2x*log2e))
__device__ __forceinline__ float sig_(float x) {
    return __builtin_amdgcn_rcpf(1.0f + __builtin_amdgcn_exp2f(x * -1.442695041f));
}
__device__ __forceinline__ float tanh_(float x) {
    return 1.0f - 2.0f * __builtin_amdgcn_rcpf(1.0f + __builtin_amdgcn_exp2f(x * 2.885390082f));
}
__device__ __forceinline__ short8 load8_f2b(const float* s) {
    const float4v f0 = *(const float4v*)s;
    const float4v f1 = *(const float4v*)(s + 4);
    short8 t;
#pragma unroll
    for (int e = 0; e < 4; ++e) {
        t[e]     = (short)f2b(f0[e]);
        t[e + 4] = (short)f2b(f1[e]);
    }
    return t;
}

// ---- producer: L0 input GEMM chunk (16 timesteps), fp32 x direct ----
// M row m = 4*tb + bb: time t0+tb, batch boff+bb -> all 16 rows valid.
__device__ __forceinline__ void xg_produce(
        const float* __restrict__ x, const float* __restrict__ wih0,
        const float* __restrict__ bih0, const float* __restrict__ bhh0,
        unsigned short* __restrict__ xg, int* __restrict__ count,
        int blk, int tch) {
    const int tid = threadIdx.x;
    const int w = tid >> 6, L = tid & 63, q = L >> 4, r = L & 15;
    const int boff = blk * 4, j = w * 16 + r;

    short8 wf[4][2]; float bias_s[4];
#pragma unroll
    for (int g = 0; g < 4; ++g) {
        const int nrow = g * HDIM + j;
#pragma unroll
        for (int kk = 0; kk < 2; ++kk)
            wf[g][kk] = load8_f2b(wih0 + (size_t)nrow * C_IN + kk * 32 + q * 8);
        bias_s[g] = bih0[nrow] + bhh0[nrow];
    }

    // A source for lane: batch boff+(r&3), time tch*16 + (r>>2) (+4 per tile)
    const float* px = x + ((size_t)(boff + (r & 3)) * S_LEN + tch * 16 + (r >> 2)) * C_IN;

#pragma unroll
    for (int tb = 0; tb < 4; ++tb) {
        const float* pa = px + (size_t)(tb * 4) * C_IN;
        short8 xa[2];
#pragma unroll
        for (int kk = 0; kk < 2; ++kk) xa[kk] = load8_f2b(pa + kk * 32 + q * 8);
        float4v a[4];
#pragma unroll
        for (int g = 0; g < 4; ++g)
            a[g] = (float4v){bias_s[g], bias_s[g], bias_s[g], bias_s[g]};
#pragma unroll
        for (int kk = 0; kk < 2; ++kk)
#pragma unroll
            for (int g = 0; g < 4; ++g)
                a[g] = __builtin_amdgcn_mfma_f32_16x16x32_bf16(xa[kk], wf[g][kk], a[g], 0, 0, 0);
        const size_t obase = ((size_t)(tch * 16 + tb * 4 + q) * NBLK + blk) * 2048
                             + (size_t)(w * 64 + r) * 4;
#pragma unroll
        for (int e = 0; e < 4; ++e) {
            short4v o;
#pragma unroll
            for (int g = 0; g < 4; ++g) o[g] = (short)f2b(a[g][e]);
            *(short4v*)(xg + obase + e * 64) = o;
        }
    }

    __threadfence();        // each thread flushes ITS stores (agent scope)
    __syncthreads();        // all stores fenced before release
    if (tid == 0)
        __hip_atomic_fetch_add(count + tch, 1, __ATOMIC_RELEASE,
                               __HIP_MEMORY_SCOPE_AGENT);
}

// ---- consumer: fused 2-layer recurrence (round-8 structure, intrinsics) ----
__device__ __forceinline__ void lstm_consume(
        const float* __restrict__ whh0_f, const float* __restrict__ wih1_f,
        const float* __restrict__ whh1_f,
        const float* __restrict__ bih1, const float* __restrict__ bhh1,
        const unsigned short* __restrict__ xg, float* __restrict__ out,
        int* __restrict__ count, unsigned short* hbuf, int blk) {
    const int tid = threadIdx.x;
    const int w = tid >> 6, L = tid & 63, q = L >> 4, r = L & 15;
    const int boff = blk * 4, j = w * 16 + r;

    // weights converted fp32->bf16 in-prologue (one-time, L3-served),
    // pinned to AGPR immediately per fragment. 48 B-frags = 192 acc regs.
    short8 whh0[4][4], wih1[4][4], whh1[4][4];
    float b1s[4];
#pragma unroll
    for (int g = 0; g < 4; ++g) {
        const size_t nrow = (size_t)(g * HDIM + j);
#pragma unroll
        for (int kk = 0; kk < 4; ++kk) {
            whh0[g][kk] = load8_f2b(whh0_f + nrow * HDIM + kk * 32 + q * 8);
            asm volatile("" : "+a"(whh0[g][kk]));
            wih1[g][kk] = load8_f2b(wih1_f + nrow * HDIM + kk * 32 + q * 8);
            asm volatile("" : "+a"(wih1[g][kk]));
            whh1[g][kk] = load8_f2b(whh1_f + nrow * HDIM + kk * 32 + q * 8);
            asm volatile("" : "+a"(whh1[g][kk]));
        }
        b1s[g] = bih1[nrow] + bhh1[nrow];
    }

    for (int idx = tid; idx < 4 * 1024; idx += 512) ((unsigned int*)hbuf)[idx] = 0u;

    float cf0 = 0.f, cf1 = 0.f;
    const int rred = r & ~3;                            // 4-way broadcast row
    const int rdoff = q * 128 + rred * 8;               // + kk*512 per K-chunk
    const int chunkbase = (j >> 3) * 128 + (j & 7);     // h write slot
    const int wslot = chunkbase + (4 * q) * 8;          // this lane's h row (m=4q)
    float* fout = out + (size_t)(boff + q) * HDIM + j;

    // wait for chunk 0, then load xg[t=0]
    while (__hip_atomic_load(count, __ATOMIC_ACQUIRE, __HIP_MEMORY_SCOPE_AGENT) < NBLK)
        __builtin_amdgcn_s_sleep(8);
    const unsigned short* pxg = xg + (size_t)blk * 2048 + (size_t)tid * 4;
    short4v xgA = *(const short4v*)pxg;
    pxg += XG_TSTRIDE;
    short4v xgB;

    __syncthreads();    // covers LDS zero + weight/xg load drain (once, cold)

    int tcur = 0;       // wave-uniform step counter (SALU)

    // iteration: L0 h0_t (if D0) THEN L1 h1_{t-1} (if D1); both read only
    // previous-iteration buffers r0/r1, write w0/w1. One barrier at the end.
    auto step = [&](auto D0_, auto D1_, auto FIN_,
                    unsigned short* r0, unsigned short* w0,
                    unsigned short* r1, unsigned short* w1,
                    short4v& xc, short4v& xn) {
        constexpr bool D0  = decltype(D0_)::value;
        constexpr bool D1  = decltype(D1_)::value;
        constexpr bool FIN = decltype(FIN_)::value;

        if constexpr (!FIN) {            // gated prefetch (vmcnt spans barrier)
            const int tn = tcur + 1;
            if (__builtin_expect((tn & 15) == 0 && tn < S_LEN, 0)) {
                while (__hip_atomic_load(count + (tn >> 4), __ATOMIC_ACQUIRE,
                                         __HIP_MEMORY_SCOPE_AGENT) < NBLK)
                    __builtin_amdgcn_s_sleep(8);
            }
            xn = *(const short4v*)pxg;
            pxg += XG_TSTRIDE;
            tcur = tn;
        }

        if constexpr (D0) {
            float4v a0[4];
#pragma unroll
            for (int g = 0; g < 4; ++g)
                a0[g] = (float4v){b2f((unsigned short)xc[g]), 0.f, 0.f, 0.f};
            __builtin_amdgcn_s_setprio(1);
#pragma unroll
            for (int kk = 0; kk < 4; ++kk) {
                const short8 h0f = *(const short8*)(r0 + kk * 512 + rdoff);
#pragma unroll
                for (int g = 0; g < 4; ++g)
                    a0[g] = __builtin_amdgcn_mfma_f32_16x16x32_bf16(h0f, whh0[g][kk], a0[g], 0, 0, 0);
            }
            __builtin_amdgcn_s_setprio(0);
            {
                const float iv = sig_(a0[0][0]);
                const float fv = sig_(a0[1][0]);
                const float gv = tanh_(a0[2][0]);
                const float ov = sig_(a0[3][0]);
                cf0 = fv * cf0 + iv * gv;
                w0[wslot] = f2b(ov * tanh_(cf0));
            }
        }

        if constexpr (D1) {
            float4v a1[4];
#pragma unroll
            for (int g = 0; g < 4; ++g) a1[g] = (float4v){b1s[g], 0.f, 0.f, 0.f};
            __builtin_amdgcn_s_setprio(1);
            // ih: input = h0_{t-1} (re-read from r0; broadcast-redirected rows)
#pragma unroll
            for (int kk = 0; kk < 4; ++kk) {
                const short8 hif = *(const short8*)(r0 + kk * 512 + rdoff);
#pragma unroll
                for (int g = 0; g < 4; ++g)
                    a1[g] = __builtin_amdgcn_mfma_f32_16x16x32_bf16(hif, wih1[g][kk], a1[g], 0, 0, 0);
            }
            // hh: h1_{t-2}
#pragma unroll
            for (int kk = 0; kk < 4; ++kk) {
                const short8 h1f = *(const short8*)(r1 + kk * 512 + rdoff);
#pragma unroll
                for (int g = 0; g < 4; ++g)
                    a1[g] = __builtin_amdgcn_mfma_f32_16x16x32_bf16(h1f, whh1[g][kk], a1[g], 0, 0, 0);
            }
            __builtin_amdgcn_s_setprio(0);
            {
                const float iv = sig_(a1[0][0]);
                const float fv = sig_(a1[1][0]);
                const float gv = tanh_(a1[2][0]);
                const float ov = sig_(a1[3][0]);
                cf1 = fv * cf1 + iv * gv;
                const float hv = ov * tanh_(cf1);
                if constexpr (FIN) fout[0] = hv;
                else w1[wslot] = f2b(hv);
            }
        }

        // lgkm-only barrier: h_t visible, but vmcnt (xg prefetch) stays in flight
        if constexpr (!FIN)
            asm volatile("s_waitcnt lgkmcnt(0)\n\ts_barrier" ::: "memory");
    };

    unsigned short* h0A = hbuf;
    unsigned short* h0B = hbuf + 2048;
    unsigned short* h1A = hbuf + 4096;
    unsigned short* h1B = hbuf + 6144;
    using T = Flag<true>; using F = Flag<false>;

    step(T{}, F{}, F{}, h0A, h0B, h1A, h1B, xgA, xgB);      // t=0: L0 only
#pragma unroll 1
    for (int k = 0; k < 255; ++k) {                          // t=1..510
        step(T{}, T{}, F{}, h0B, h0A, h1B, h1A, xgB, xgA);
        step(T{}, T{}, F{}, h0A, h0B, h1A, h1B, xgA, xgB);
    }
    step(T{}, T{}, F{}, h0B, h0A, h1B, h1A, xgB, xgA);      // t=511
    step(F{}, T{}, T{}, h0A, h0B, h1A, h1B, xgA, xgB);      // t=512: L1 only -> out
}

__global__ __launch_bounds__(512, 2)
void lstm_pipe(const float* __restrict__ x, const float* __restrict__ wih0,
               const float* __restrict__ bih0, const float* __restrict__ bhh0,
               const float* __restrict__ whh0_f,
               const float* __restrict__ wih1_f, const float* __restrict__ whh1_f,
               const float* __restrict__ bih1, const float* __restrict__ bhh1,
               unsigned short* __restrict__ xg, int* __restrict__ count,
               float* __restrict__ out) {
    __shared__ __align__(16) unsigned short hbuf[4 * 2048];
    const int bid = blockIdx.x;
    if (bid >= NBLK) {
        const int p = bid - NBLK;
        xg_produce(x, wih0, bih0, bhh0, xg, count, p & 63, p >> 6);
    } else {
        lstm_consume(whh0_f, wih1_f, whh1_f, bih1, bhh1, xg, out, count, hbuf, bid);
    }
}

// ---- workspace layout (bytes) ----
//     0 : count   512  (32 ints used)
//   512 : xg  134742016  (513 t-slots x 262144 B; 1 pad slot for tail prefetch)

extern "C" void kernel_launch(void* const* d_in, const int* in_sizes, int n_in,
                              void* d_out, int out_size, void* d_ws, size_t ws_size,
                              hipStream_t stream) {
    const float* x    = (const float*)d_in[0];
    const float* wih0 = (const float*)d_in[1];
    const float* whh0 = (const float*)d_in[2];
    const float* bih0 = (const float*)d_in[3];
    const float* bhh0 = (const float*)d_in[4];
    const float* wih1 = (const float*)d_in[5];
    const float* whh1 = (const float*)d_in[6];
    const float* bih1 = (const float*)d_in[7];
    const float* bhh1 = (const float*)d_in[8];

    char* ws = (char*)d_ws;
    int*            count = (int*)ws;
    unsigned short* xgp   = (unsigned short*)(ws + 512);

    hipMemsetAsync(count, 0, 512, stream);
    lstm_pipe<<<NBLK + NPROD, 512, 0, stream>>>(
        x, wih0, bih0, bhh0, whh0, wih1, whh1, bih1, bhh1,
        xgp, count, (float*)d_out);
}

// Round 12
// 2778.598 us; speedup vs baseline: 1.1068x; 1.1068x over previous
//
#include <hip/hip_runtime.h>
#include <cstdint>
#include <cstddef>

// LSTM B=256,S=512,C=64,H=128, 2 layers, gates i,f,g,o (torch order).
// Round 15: single-launch overlap, round-0-proven gating discipline.
// Round-11 failure (3ms) diagnosed: (1) all-wave agent-acquire spin ->
// buffer_inv (L2 invalidate) storm from 512 waves polling; (2) 2048-block
// producer herd each ending in threadfence (wbl2) with late chunks
// dispatched last. Fixes:
//   - 256 FAT producers (blk 0-63 x qtr 0-3), each 128 timesteps, ONE
//     threadfence + release flag at end. Grid 320 <= 512 resident slots ->
//     everything starts at t=0; producers done ~15-40us, consumer needs
//     qtr 1 at ~140us -> no steady-state spin.
//   - consumer gates per-(blk,qtr) at 128-step boundaries only (3+init),
//     tid0 acquire-spin + __syncthreads (round-0 baseline pattern).
// Consumer inner loop = round-8 passing body (intrinsic MFMA, phase-split,
// 192 AGPR-pinned weight frags, 4-way broadcast A-reads, 1 lgkm-only
// barrier/step, xg prefetch spanning the barrier).
//
// MFMA 16x16x32 bf16 frags (verified rounds 1-14):
//   A[m=lane&15][k=(lane>>4)*8+j], B == W[n=lane&15][k] 16B row chunk,
//   D[m=4*(lane>>4)+reg][n=lane&15]
// Consumer valid tile rows: m&3==0 (batch row = m>>2).

#define S_LEN 512
#define B_SZ  256
#define C_IN  64
#define HDIM  128
#define NBLK  64                     // consumer blocks, 4 batch rows each
#define NPROD (64 * 4)               // fat producer blocks (qtr = 128 steps)
#define XG_TSTRIDE (64 * 512 * 4)    // shorts per timestep slot of xg (=131072)

using short4v = __attribute__((ext_vector_type(4))) short;   // 4 bf16
using short8  = __attribute__((ext_vector_type(8))) short;   // 8 bf16
using float4v = __attribute__((ext_vector_type(4))) float;

template<bool V> struct Flag { static constexpr bool value = V; };

__device__ __forceinline__ unsigned short f2b(float f) {
    union { float f; unsigned int u; } v; v.f = f;
    unsigned int u = v.u;
    return (unsigned short)((u + 0x7FFFu + ((u >> 16) & 1u)) >> 16);
}
__device__ __forceinline__ float b2f(unsigned short s) {
    union { unsigned int u; float f; } v; v.u = ((unsigned int)s) << 16;
    return v.f;
}
// lean activations: sigma = rcp(1+exp2(-x*log2e)), tanh = 1-2*rcp(1+exp2(2x*log2e))
__device__ __forceinline__ float sig_(float x) {
    return __builtin_amdgcn_rcpf(1.0f + __builtin_amdgcn_exp2f(x * -1.442695041f));
}
__device__ __forceinline__ float tanh_(float x) {
    return 1.0f - 2.0f * __builtin_amdgcn_rcpf(1.0f + __builtin_amdgcn_exp2f(x * 2.885390082f));
}
__device__ __forceinline__ short8 load8_f2b(const float* s) {
    const float4v f0 = *(const float4v*)s;
    const float4v f1 = *(const float4v*)(s + 4);
    short8 t;
#pragma unroll
    for (int e = 0; e < 4; ++e) {
        t[e]     = (short)f2b(f0[e]);
        t[e + 4] = (short)f2b(f1[e]);
    }
    return t;
}

// ---- producer: L0 input GEMM, 128 timesteps (32 4b x 4t M-tiles) ----
// M row m = 4*tb + bb: time t0+tb, batch boff+bb -> all 16 rows valid.
__device__ __forceinline__ void xg_produce(
        const float* __restrict__ x, const float* __restrict__ wih0,
        const float* __restrict__ bih0, const float* __restrict__ bhh0,
        unsigned short* __restrict__ xg, int* __restrict__ flags,
        int blk, int qtr) {
    const int tid = threadIdx.x;
    const int w = tid >> 6, L = tid & 63, q = L >> 4, r = L & 15;
    const int boff = blk * 4, j = w * 16 + r;

    short8 wf[4][2]; float bias_s[4];
#pragma unroll
    for (int g = 0; g < 4; ++g) {
        const int nrow = g * HDIM + j;
#pragma unroll
        for (int kk = 0; kk < 2; ++kk)
            wf[g][kk] = load8_f2b(wih0 + (size_t)nrow * C_IN + kk * 32 + q * 8);
        bias_s[g] = bih0[nrow] + bhh0[nrow];
    }

    // A source for lane: batch boff+(r&3), time qtr*128 + (r>>2) (+4 per tile)
    const float* px = x + ((size_t)(boff + (r & 3)) * S_LEN + qtr * 128 + (r >> 2)) * C_IN;

#pragma unroll 4
    for (int tt = 0; tt < 32; ++tt) {
        const float* pa = px + (size_t)(tt * 4) * C_IN;
        short8 xa[2];
#pragma unroll
        for (int kk = 0; kk < 2; ++kk) xa[kk] = load8_f2b(pa + kk * 32 + q * 8);
        float4v a[4];
#pragma unroll
        for (int g = 0; g < 4; ++g)
            a[g] = (float4v){bias_s[g], bias_s[g], bias_s[g], bias_s[g]};
#pragma unroll
        for (int kk = 0; kk < 2; ++kk)
#pragma unroll
            for (int g = 0; g < 4; ++g)
                a[g] = __builtin_amdgcn_mfma_f32_16x16x32_bf16(xa[kk], wf[g][kk], a[g], 0, 0, 0);
        const size_t obase = ((size_t)(qtr * 128 + tt * 4 + q) * NBLK + blk) * 2048
                             + (size_t)(w * 64 + r) * 4;
#pragma unroll
        for (int e = 0; e < 4; ++e) {
            short4v o;
#pragma unroll
            for (int g = 0; g < 4; ++g) o[g] = (short)f2b(a[g][e]);
            *(short4v*)(xg + obase + e * 64) = o;
        }
    }

    __threadfence();        // flush xg stores to coherence point (once/block)
    __syncthreads();        // all threads fenced before release
    if (tid == 0)
        __hip_atomic_store(flags + qtr * NBLK + blk, 1, __ATOMIC_RELEASE,
                           __HIP_MEMORY_SCOPE_AGENT);
}

// ---- consumer: fused 2-layer recurrence (round-8 structure, intrinsics) ----
__device__ __forceinline__ void lstm_consume(
        const float* __restrict__ whh0_f, const float* __restrict__ wih1_f,
        const float* __restrict__ whh1_f,
        const float* __restrict__ bih1, const float* __restrict__ bhh1,
        const unsigned short* __restrict__ xg, float* __restrict__ out,
        int* __restrict__ flags, unsigned short* hbuf, int blk) {
    const int tid = threadIdx.x;
    const int w = tid >> 6, L = tid & 63, q = L >> 4, r = L & 15;
    const int boff = blk * 4, j = w * 16 + r;

    // weights converted fp32->bf16 in-prologue (one-time, L3-served),
    // pinned to AGPR immediately per fragment. 48 B-frags = 192 acc regs.
    short8 whh0[4][4], wih1[4][4], whh1[4][4];
    float b1s[4];
#pragma unroll
    for (int g = 0; g < 4; ++g) {
        const size_t nrow = (size_t)(g * HDIM + j);
#pragma unroll
        for (int kk = 0; kk < 4; ++kk) {
            whh0[g][kk] = load8_f2b(whh0_f + nrow * HDIM + kk * 32 + q * 8);
            asm volatile("" : "+a"(whh0[g][kk]));
            wih1[g][kk] = load8_f2b(wih1_f + nrow * HDIM + kk * 32 + q * 8);
            asm volatile("" : "+a"(wih1[g][kk]));
            whh1[g][kk] = load8_f2b(whh1_f + nrow * HDIM + kk * 32 + q * 8);
            asm volatile("" : "+a"(whh1[g][kk]));
        }
        b1s[g] = bih1[nrow] + bhh1[nrow];
    }

    for (int idx = tid; idx < 4 * 1024; idx += 512) ((unsigned int*)hbuf)[idx] = 0u;

    float cf0 = 0.f, cf1 = 0.f;
    const int rred = r & ~3;                            // 4-way broadcast row
    const int rdoff = q * 128 + rred * 8;               // + kk*512 per K-chunk
    const int chunkbase = (j >> 3) * 128 + (j & 7);     // h write slot
    const int wslot = chunkbase + (4 * q) * 8;          // this lane's h row (m=4q)
    float* fout = out + (size_t)(boff + q) * HDIM + j;

    // gate qtr 0 (tid0 acquire-spin + syncthreads: round-0 proven pattern)
    if (tid == 0)
        while (__hip_atomic_load(flags + blk, __ATOMIC_ACQUIRE,
                                 __HIP_MEMORY_SCOPE_AGENT) == 0)
            __builtin_amdgcn_s_sleep(8);
    __syncthreads();    // gate broadcast + covers LDS zero

    const unsigned short* pxg = xg + (size_t)blk * 2048 + (size_t)tid * 4;
    short4v xgA = *(const short4v*)pxg;
    pxg += XG_TSTRIDE;
    short4v xgB;

    int tcur = 0;       // wave-uniform step counter (SALU)

    // iteration: L0 h0_t (if D0) THEN L1 h1_{t-1} (if D1); both read only
    // previous-iteration buffers r0/r1, write w0/w1. One barrier at the end.
    auto step = [&](auto D0_, auto D1_, auto FIN_,
                    unsigned short* r0, unsigned short* w0,
                    unsigned short* r1, unsigned short* w1,
                    short4v& xc, short4v& xn) {
        constexpr bool D0  = decltype(D0_)::value;
        constexpr bool D1  = decltype(D1_)::value;
        constexpr bool FIN = decltype(FIN_)::value;

        if constexpr (!FIN) {            // gated prefetch (vmcnt spans barrier)
            const int tn = tcur + 1;
            if (__builtin_expect((tn & 127) == 0 && tn < S_LEN, 0)) {
                if (tid == 0)
                    while (__hip_atomic_load(flags + (tn >> 7) * NBLK + blk,
                                             __ATOMIC_ACQUIRE,
                                             __HIP_MEMORY_SCOPE_AGENT) == 0)
                        __builtin_amdgcn_s_sleep(8);
                __syncthreads();
            }
            xn = *(const short4v*)pxg;
            pxg += XG_TSTRIDE;
            tcur = tn;
        }

        if constexpr (D0) {
            float4v a0[4];
#pragma unroll
            for (int g = 0; g < 4; ++g)
                a0[g] = (float4v){b2f((unsigned short)xc[g]), 0.f, 0.f, 0.f};
            __builtin_amdgcn_s_setprio(1);
#pragma unroll
            for (int kk = 0; kk < 4; ++kk) {
                const short8 h0f = *(const short8*)(r0 + kk * 512 + rdoff);
#pragma unroll
                for (int g = 0; g < 4; ++g)
                    a0[g] = __builtin_amdgcn_mfma_f32_16x16x32_bf16(h0f, whh0[g][kk], a0[g], 0, 0, 0);
            }
            __builtin_amdgcn_s_setprio(0);
            {
                const float iv = sig_(a0[0][0]);
                const float fv = sig_(a0[1][0]);
                const float gv = tanh_(a0[2][0]);
                const float ov = sig_(a0[3][0]);
                cf0 = fv * cf0 + iv * gv;
                w0[wslot] = f2b(ov * tanh_(cf0));
            }
        }

        if constexpr (D1) {
            float4v a1[4];
#pragma unroll
            for (int g = 0; g < 4; ++g) a1[g] = (float4v){b1s[g], 0.f, 0.f, 0.f};
            __builtin_amdgcn_s_setprio(1);
            // ih: input = h0_{t-1} (re-read from r0; broadcast-redirected rows)
#pragma unroll
            for (int kk = 0; kk < 4; ++kk) {
                const short8 hif = *(const short8*)(r0 + kk * 512 + rdoff);
#pragma unroll
                for (int g = 0; g < 4; ++g)
                    a1[g] = __builtin_amdgcn_mfma_f32_16x16x32_bf16(hif, wih1[g][kk], a1[g], 0, 0, 0);
            }
            // hh: h1_{t-2}
#pragma unroll
            for (int kk = 0; kk < 4; ++kk) {
                const short8 h1f = *(const short8*)(r1 + kk * 512 + rdoff);
#pragma unroll
                for (int g = 0; g < 4; ++g)
                    a1[g] = __builtin_amdgcn_mfma_f32_16x16x32_bf16(h1f, whh1[g][kk], a1[g], 0, 0, 0);
            }
            __builtin_amdgcn_s_setprio(0);
            {
                const float iv = sig_(a1[0][0]);
                const float fv = sig_(a1[1][0]);
                const float gv = tanh_(a1[2][0]);
                const float ov = sig_(a1[3][0]);
                cf1 = fv * cf1 + iv * gv;
                const float hv = ov * tanh_(cf1);
                if constexpr (FIN) fout[0] = hv;
                else w1[wslot] = f2b(hv);
            }
        }

        // lgkm-only barrier: h_t visible, but vmcnt (xg prefetch) stays in flight
        if constexpr (!FIN)
            asm volatile("s_waitcnt lgkmcnt(0)\n\ts_barrier" ::: "memory");
    };

    unsigned short* h0A = hbuf;
    unsigned short* h0B = hbuf + 2048;
    unsigned short* h1A = hbuf + 4096;
    unsigned short* h1B = hbuf + 6144;
    using T = Flag<true>; using F = Flag<false>;

    step(T{}, F{}, F{}, h0A, h0B, h1A, h1B, xgA, xgB);      // t=0: L0 only
#pragma unroll 1
    for (int k = 0; k < 255; ++k) {                          // t=1..510
        step(T{}, T{}, F{}, h0B, h0A, h1B, h1A, xgB, xgA);
        step(T{}, T{}, F{}, h0A, h0B, h1A, h1B, xgA, xgB);
    }
    step(T{}, T{}, F{}, h0B, h0A, h1B, h1A, xgB, xgA);      // t=511
    step(F{}, T{}, T{}, h0A, h0B, h1A, h1B, xgA, xgB);      // t=512: L1 only -> out
}

__global__ __launch_bounds__(512, 2)
void lstm_pipe(const float* __restrict__ x, const float* __restrict__ wih0,
               const float* __restrict__ bih0, const float* __restrict__ bhh0,
               const float* __restrict__ whh0_f,
               const float* __restrict__ wih1_f, const float* __restrict__ whh1_f,
               const float* __restrict__ bih1, const float* __restrict__ bhh1,
               unsigned short* __restrict__ xg, int* __restrict__ flags,
               float* __restrict__ out) {
    __shared__ __align__(16) unsigned short hbuf[4 * 2048];
    const int bid = blockIdx.x;
    if (bid >= NBLK) {
        const int p = bid - NBLK;
        xg_produce(x, wih0, bih0, bhh0, xg, flags, p & 63, p >> 6);
    } else {
        lstm_consume(whh0_f, wih1_f, whh1_f, bih1, bhh1, xg, out, flags, hbuf, bid);
    }
}

// ---- workspace layout (bytes) ----
//     0 : flags  1024  (4 qtr x 64 blk ints)
//  1024 : xg  134742016  (513 t-slots x 262144 B; 1 pad slot for tail prefetch)

extern "C" void kernel_launch(void* const* d_in, const int* in_sizes, int n_in,
                              void* d_out, int out_size, void* d_ws, size_t ws_size,
                              hipStream_t stream) {
    const float* x    = (const float*)d_in[0];
    const float* wih0 = (const float*)d_in[1];
    const float* whh0 = (const float*)d_in[2];
    const float* bih0 = (const float*)d_in[3];
    const float* bhh0 = (const float*)d_in[4];
    const float* wih1 = (const float*)d_in[5];
    const float* whh1 = (const float*)d_in[6];
    const float* bih1 = (const float*)d_in[7];
    const float* bhh1 = (const float*)d_in[8];

    char* ws = (char*)d_ws;
    int*            flags = (int*)ws;
    unsigned short* xgp   = (unsigned short*)(ws + 1024);

    hipMemsetAsync(flags, 0, 1024, stream);
    lstm_pipe<<<NBLK + NPROD, 512, 0, stream>>>(
        x, wih0, bih0, bhh0, whh0, wih1, whh1, bih1, bhh1,
        xgp, flags, (float*)d_out);
}